// Round 1
// baseline (2037.102 us; speedup 1.0000x reference)
//
#include <hip/hip_runtime.h>
#include <cmath>

#define D_MODEL 1024
#define D_STATE 16
#define D_INNER 2048
#define NB 4
#define SEQL 2048
#define ROWS (NB*SEQL)        // 8192
#define XZ_LD (2*D_INNER)     // 4096

__device__ __forceinline__ float sigmoidf_(float v) { return 1.0f / (1.0f + __expf(-v)); }

// ---------------- fp32 SGEMM: C(M,N) = A(M,K) * B(N,K)^T, row-major, NT ----------------
// 128x128 block tile, 256 threads, 8x8 per-thread micro-tile, BK=8.
__global__ __launch_bounds__(256) void sgemm_nt(
    const float* __restrict__ A, int lda,
    const float* __restrict__ B, int ldb,
    float* __restrict__ C, int ldc,
    int K)
{
    __shared__ float As[8][128];
    __shared__ float Bs[8][128];
    const int tid = threadIdx.x;
    const int bm = blockIdx.y * 128;
    const int bn = blockIdx.x * 128;
    const int lr = tid >> 1;           // 0..127 (row within tile for loading)
    const int lk = (tid & 1) << 2;     // 0 or 4
    const float* Ap = A + (size_t)(bm + lr) * lda + lk;
    const float* Bp = B + (size_t)(bn + lr) * ldb + lk;
    const int tx = tid & 15, ty = tid >> 4;
    float acc[8][8] = {};

    for (int k0 = 0; k0 < K; k0 += 8) {
        const float4 av = *(const float4*)(Ap + k0);
        const float4 bv = *(const float4*)(Bp + k0);
        __syncthreads();   // previous iteration's compute done before overwrite
        As[lk+0][lr] = av.x; As[lk+1][lr] = av.y; As[lk+2][lr] = av.z; As[lk+3][lr] = av.w;
        Bs[lk+0][lr] = bv.x; Bs[lk+1][lr] = bv.y; Bs[lk+2][lr] = bv.z; Bs[lk+3][lr] = bv.w;
        __syncthreads();
#pragma unroll
        for (int kk = 0; kk < 8; ++kk) {
            float a[8], b[8];
            *(float4*)&a[0] = *(const float4*)&As[kk][ty * 4];
            *(float4*)&a[4] = *(const float4*)&As[kk][64 + ty * 4];
            *(float4*)&b[0] = *(const float4*)&Bs[kk][tx * 4];
            *(float4*)&b[4] = *(const float4*)&Bs[kk][64 + tx * 4];
#pragma unroll
            for (int i = 0; i < 8; ++i)
#pragma unroll
                for (int j = 0; j < 8; ++j)
                    acc[i][j] = fmaf(a[i], b[j], acc[i][j]);
        }
    }
#pragma unroll
    for (int i = 0; i < 8; ++i) {
        int m = bm + ((i < 4) ? (ty * 4 + i) : (64 + ty * 4 + i - 4));
        float* Cr = C + (size_t)m * ldc + bn;
        *(float4*)&Cr[tx * 4]      = make_float4(acc[i][0], acc[i][1], acc[i][2], acc[i][3]);
        *(float4*)&Cr[64 + tx * 4] = make_float4(acc[i][4], acc[i][5], acc[i][6], acc[i][7]);
    }
}

// ---------------- causal depthwise conv (D_CONV=4) + SiLU ----------------
// x_proj lives in xz cols [0, D_INNER), ld = XZ_LD. One float4 (4 channels) per thread.
__global__ __launch_bounds__(256) void conv_silu_k(
    const float* __restrict__ xz, const float* __restrict__ conv_w,
    const float* __restrict__ conv_b, float* __restrict__ x_conv)
{
    int idx = blockIdx.x * 256 + threadIdx.x;   // ROWS * 512 total
    int q = idx & 511;
    int r = idx >> 9;                            // global row = b*SEQL + t
    int b = r >> 11, t = r & (SEQL - 1);
    int d0 = q << 2;
    float w[4][4];
#pragma unroll
    for (int c = 0; c < 4; ++c) *(float4*)w[c] = *(const float4*)&conv_w[(d0 + c) * 4];
    float4 acc = *(const float4*)&conv_b[d0];
    const float* xp = xz + (size_t)(b * SEQL) * XZ_LD + d0;
#pragma unroll
    for (int k = 0; k < 4; ++k) {
        int t2 = t - 3 + k;
        if (t2 >= 0) {
            float4 v = *(const float4*)(xp + (size_t)t2 * XZ_LD);
            acc.x = fmaf(v.x, w[0][k], acc.x);
            acc.y = fmaf(v.y, w[1][k], acc.y);
            acc.z = fmaf(v.z, w[2][k], acc.z);
            acc.w = fmaf(v.w, w[3][k], acc.w);
        }
    }
    acc.x *= sigmoidf_(acc.x);
    acc.y *= sigmoidf_(acc.y);
    acc.z *= sigmoidf_(acc.z);
    acc.w *= sigmoidf_(acc.w);
    *(float4*)&x_conv[(size_t)r * D_INNER + d0] = acc;
}

// ---------------- x_proj: 33 dot-products of length 2048 per row; then dt/A_bar/B_bar/C ----------------
// One wave per row, 4 rows per 256-thread block. x row held in registers (32 f/lane).
__global__ __launch_bounds__(256) void proj_k(
    const float* __restrict__ x_conv, const float* __restrict__ W_xproj,
    const float* __restrict__ A_log,
    float* __restrict__ Abar, float* __restrict__ Bbar, float* __restrict__ Cmat)
{
    __shared__ float sdbl[4][33];
    int tid = threadIdx.x;
    int w = tid >> 6, lane = tid & 63;
    int row = blockIdx.x * 4 + w;
    const float* xrow = x_conv + (size_t)row * D_INNER;
    float4 xr[8];
#pragma unroll
    for (int it = 0; it < 8; ++it)
        xr[it] = *(const float4*)&xrow[it * 256 + lane * 4];

    for (int j = 0; j < 33; ++j) {
        const float* wrow = W_xproj + j * D_INNER;
        float accv = 0.f;
#pragma unroll
        for (int it = 0; it < 8; ++it) {
            float4 wv = *(const float4*)&wrow[it * 256 + lane * 4];
            accv = fmaf(xr[it].x, wv.x, accv);
            accv = fmaf(xr[it].y, wv.y, accv);
            accv = fmaf(xr[it].z, wv.z, accv);
            accv = fmaf(xr[it].w, wv.w, accv);
        }
#pragma unroll
        for (int off = 32; off; off >>= 1) accv += __shfl_xor(accv, off);
        if (lane == 0) sdbl[w][j] = accv;
    }
    __syncthreads();
    if (tid < 64) {
        int w2 = tid >> 4, s = tid & 15;
        int row2 = blockIdx.x * 4 + w2;
        float draw = sdbl[w2][32];
        float sp = (draw > 20.f) ? draw : log1pf(__expf(draw));
        float dt = fminf(fmaxf(sp, 0.001f), 0.1f);
        float Aa = -__expf(A_log[s]);
        float dtA = fminf(fmaxf(dt * Aa, -20.f), 0.f);
        Abar[row2 * 16 + s] = __expf(dtA);
        float bb = dt * sdbl[w2][s];
        Bbar[row2 * 16 + s] = fminf(fmaxf(bb, -10.f), 10.f);
        Cmat[row2 * 16 + s] = sdbl[w2][16 + s];
    }
}

// ---------------- sequential SSM scan + epilogue, fused ----------------
// grid (D_INNER/256, NB); thread owns one channel d, h[16] in registers.
// Double-buffered LDS staging of x_conv, z, and per-t params (16-step chunks)
// so HBM latency hides under compute. Writes final y into xz cols [0, D_INNER).
#define TCH 16
__global__ __launch_bounds__(256) void scan_k(
    const float* __restrict__ x_conv, float* __restrict__ xz,
    const float* __restrict__ Abar, const float* __restrict__ Bbar,
    const float* __restrict__ Cmat, const float* __restrict__ D_param)
{
    __shared__ float sX[2][TCH * 256];
    __shared__ float sZ[2][TCH * 256];
    __shared__ float sP[2][TCH * 48];  // per t: [0..15]=A_bar [16..31]=B_bar [32..47]=C
    int tid = threadIdx.x;
    int b = blockIdx.y;
    int dbase = blockIdx.x * 256;
    int d = dbase + tid;
    const float* xc = x_conv + (size_t)(b * SEQL) * D_INNER + dbase;
    const float* zp = xz + (size_t)(b * SEQL) * XZ_LD + D_INNER + dbase;

    auto stage = [&](int buf, int tc) {
        int t0 = tc * TCH;
#pragma unroll
        for (int i = 0; i < TCH; ++i) {
            sX[buf][i * 256 + tid] = xc[(size_t)(t0 + i) * D_INNER + tid];
            sZ[buf][i * 256 + tid] = zp[(size_t)(t0 + i) * XZ_LD + tid];
        }
        int base = (b * SEQL + t0) * 16;
        int i = tid;            // TCH*16 == 256
        int tt = i >> 4, ss = i & 15;
        sP[buf][tt * 48 + ss]      = Abar[base + i];
        sP[buf][tt * 48 + 16 + ss] = Bbar[base + i];
        sP[buf][tt * 48 + 32 + ss] = Cmat[base + i];
    };

    stage(0, 0);
    float h[16];
#pragma unroll
    for (int s = 0; s < 16; ++s) h[s] = 0.f;
    float Dp = D_param[d];

    for (int tc = 0; tc < SEQL / TCH; ++tc) {
        int buf = tc & 1;
        __syncthreads();                      // staging of `buf` complete
        if (tc + 1 < SEQL / TCH) stage(buf ^ 1, tc + 1);
#pragma unroll
        for (int i = 0; i < TCH; ++i) {
            float x = sX[buf][i * 256 + tid];
            float z = sZ[buf][i * 256 + tid];
            float Av[16], Bv[16], Cv[16];
            const float* P = &sP[buf][i * 48];
#pragma unroll
            for (int q = 0; q < 4; ++q) {
                *(float4*)&Av[q * 4] = *(const float4*)&P[q * 4];
                *(float4*)&Bv[q * 4] = *(const float4*)&P[16 + q * 4];
                *(float4*)&Cv[q * 4] = *(const float4*)&P[32 + q * 4];
            }
            float y = 0.f;
#pragma unroll
            for (int s = 0; s < 16; ++s) {
                float hv = fmaf(Bv[s], x, Av[s] * h[s]);
                hv = fminf(fmaxf(hv, -100.f), 100.f);
                h[s] = hv;
                y = fmaf(hv, Cv[s], y);
            }
            float zs = z * sigmoidf_(z);
            float o = fmaf(x, Dp, y * zs);
            xz[(size_t)(b * SEQL + tc * TCH + i) * XZ_LD + d] = o;
        }
    }
}

extern "C" void kernel_launch(void* const* d_in, const int* in_sizes, int n_in,
                              void* d_out, int out_size, void* d_ws, size_t ws_size,
                              hipStream_t stream) {
    const float* x       = (const float*)d_in[0];
    const float* W_in    = (const float*)d_in[1];
    const float* conv_w  = (const float*)d_in[2];
    const float* conv_b  = (const float*)d_in[3];
    const float* W_xproj = (const float*)d_in[4];
    const float* A_log   = (const float*)d_in[5];
    const float* D_param = (const float*)d_in[6];
    const float* W_out   = (const float*)d_in[7];
    float* out = (float*)d_out;

    float* ws = (float*)d_ws;
    float* xz     = ws;                                  // ROWS * 4096
    float* x_conv = xz + (size_t)ROWS * XZ_LD;           // ROWS * 2048
    float* Abar   = x_conv + (size_t)ROWS * D_INNER;     // ROWS * 16
    float* Bbar   = Abar + (size_t)ROWS * 16;
    float* Cm     = Bbar + (size_t)ROWS * 16;

    // 1) xz = x @ W_in^T   (8192 x 4096, K=1024)
    sgemm_nt<<<dim3(4096 / 128, ROWS / 128), 256, 0, stream>>>(
        x, D_MODEL, W_in, D_MODEL, xz, XZ_LD, D_MODEL);
    // 2) causal conv + silu -> x_conv
    conv_silu_k<<<ROWS * 512 / 256, 256, 0, stream>>>(xz, conv_w, conv_b, x_conv);
    // 3) x_proj -> A_bar, B_bar, C
    proj_k<<<ROWS / 4, 256, 0, stream>>>(x_conv, W_xproj, A_log, Abar, Bbar, Cm);
    // 4) scan + gating epilogue -> y (stored into xz cols [0, D_INNER))
    scan_k<<<dim3(D_INNER / 256, NB), 256, 0, stream>>>(x_conv, xz, Abar, Bbar, Cm, D_param);
    // 5) out = y @ W_out^T  (8192 x 1024, K=2048, lda=4096 strided)
    sgemm_nt<<<dim3(1024 / 128, ROWS / 128), 256, 0, stream>>>(
        xz, XZ_LD, W_out, D_INNER, out, D_MODEL, D_INNER);
}

// Round 3
// 1036.387 us; speedup vs baseline: 1.9656x; 1.9656x over previous
//
#include <hip/hip_runtime.h>
#include <cmath>

#define D_MODEL 1024
#define D_STATE 16
#define D_INNER 2048
#define NB 4
#define SEQL 2048
#define ROWS (NB*SEQL)        // 8192
#define XZ_LD (2*D_INNER)     // 4096

typedef __attribute__((ext_vector_type(8))) short short8;
typedef __attribute__((ext_vector_type(4))) float f32x4;

__device__ __forceinline__ float sigmoidf_(float v) { return 1.0f / (1.0f + __expf(-v)); }

__device__ __forceinline__ unsigned short bf16rne(float f) {
    unsigned u = __float_as_uint(f);
    unsigned r = (u + 0x7FFFu + ((u >> 16) & 1u)) >> 16;
    return (unsigned short)r;
}

// ---------------- fp32 -> (hi, lo) bf16 split ----------------
__global__ __launch_bounds__(256) void cvt_k(const float4* __restrict__ in,
    ushort4* __restrict__ hi, ushort4* __restrict__ lo, int n4)
{
    int i = blockIdx.x * 256 + threadIdx.x;
    if (i >= n4) return;
    float4 v = in[i];
    ushort4 h, l;
    h.x = bf16rne(v.x); l.x = bf16rne(v.x - __uint_as_float((unsigned)h.x << 16));
    h.y = bf16rne(v.y); l.y = bf16rne(v.y - __uint_as_float((unsigned)h.y << 16));
    h.z = bf16rne(v.z); l.z = bf16rne(v.z - __uint_as_float((unsigned)h.z << 16));
    h.w = bf16rne(v.w); l.w = bf16rne(v.w - __uint_as_float((unsigned)h.w << 16));
    hi[i] = h; lo[i] = l;
}

// ---------------- bf16x3 split-precision MFMA GEMM (NT): C = A*B^T ----------------
// A: M x K (hi/lo bf16, row-major, ld=lda), B: N x K (hi/lo), C fp32 M x N (ld=ldc).
// 128x128 tile, 4 waves (2x2 of 64x64), BK=32, 16x16x32 bf16 MFMA, 3 MFMAs per frag pair
// (hh, lh, hl; ll term ~2^-18 dropped).
// LDS: k-slot-major [8 slots][128 rows][8 elems]; slots 0..3 = hi k-slices, 4..7 = lo.
// global_load_lds writes linearly (wave-uniform base + lane*16B); fragment ds_read_b128
// is conflict-free (each 16-lane group reads a contiguous 256B stripe).
#define GLDS(gp, lp) __builtin_amdgcn_global_load_lds( \
    (const __attribute__((address_space(1))) void*)(gp), \
    (__attribute__((address_space(3))) void*)(lp), 16, 0, 0)

__global__ __launch_bounds__(256) void gemm_hilo(
    const unsigned short* __restrict__ Ah, const unsigned short* __restrict__ Al, int lda,
    const unsigned short* __restrict__ Bh, const unsigned short* __restrict__ Bl, int ldb,
    float* __restrict__ C, int ldc, int K)
{
    __shared__ __align__(16) unsigned short sA[8 * 128 * 8];   // 16 KiB
    __shared__ __align__(16) unsigned short sB[8 * 128 * 8];   // 16 KiB
    const int tid = threadIdx.x;
    const int bm = blockIdx.y * 128, bn = blockIdx.x * 128;
    const int wave = tid >> 6, lane = tid & 63;
    const int wr = (wave >> 1) * 64, wc = (wave & 1) * 64;
    const int fr = lane & 15, kq = lane >> 4;

    // staging: chunk c = run*256 + tid; slot s = c>>7 (0..7), row r = c&127
    const unsigned short* agp[4];
    const unsigned short* bgp[4];
#pragma unroll
    for (int run = 0; run < 4; ++run) {
        int c = run * 256 + tid, s = c >> 7, r = c & 127;
        const unsigned short* ab = (s < 4) ? Ah : Al;
        const unsigned short* bb = (s < 4) ? Bh : Bl;
        agp[run] = ab + (size_t)(bm + r) * lda + (s & 3) * 8;
        bgp[run] = bb + (size_t)(bn + r) * ldb + (s & 3) * 8;
    }

    f32x4 zero = {0.f, 0.f, 0.f, 0.f};
    f32x4 acc[4][4];
#pragma unroll
    for (int m = 0; m < 4; ++m)
#pragma unroll
        for (int n = 0; n < 4; ++n) acc[m][n] = zero;

    for (int k0 = 0; k0 < K; k0 += 32) {
        __syncthreads();   // all waves done reading LDS from previous step
#pragma unroll
        for (int run = 0; run < 4; ++run) {
            unsigned lds_off = (unsigned)(run * 256 + (tid & 192)) * 8;  // ushort units
            GLDS(agp[run], sA + lds_off);
            GLDS(bgp[run], sB + lds_off);
            agp[run] += 32; bgp[run] += 32;
        }
        __syncthreads();   // implicit vmcnt(0) drain -> staged data visible

        short8 ahf[4], alf[4], bhf[4], blf[4];
#pragma unroll
        for (int m = 0; m < 4; ++m) {
            int ra = wr + m * 16 + fr;
            ahf[m] = *(const short8*)&sA[(kq * 128 + ra) * 8];
            alf[m] = *(const short8*)&sA[((kq + 4) * 128 + ra) * 8];
        }
#pragma unroll
        for (int n = 0; n < 4; ++n) {
            int rb = wc + n * 16 + fr;
            bhf[n] = *(const short8*)&sB[(kq * 128 + rb) * 8];
            blf[n] = *(const short8*)&sB[((kq + 4) * 128 + rb) * 8];
        }
#pragma unroll
        for (int m = 0; m < 4; ++m)
#pragma unroll
            for (int n = 0; n < 4; ++n)
                acc[m][n] = __builtin_amdgcn_mfma_f32_16x16x32_bf16(ahf[m], bhf[n], acc[m][n], 0, 0, 0);
#pragma unroll
        for (int m = 0; m < 4; ++m)
#pragma unroll
            for (int n = 0; n < 4; ++n)
                acc[m][n] = __builtin_amdgcn_mfma_f32_16x16x32_bf16(alf[m], bhf[n], acc[m][n], 0, 0, 0);
#pragma unroll
        for (int m = 0; m < 4; ++m)
#pragma unroll
            for (int n = 0; n < 4; ++n)
                acc[m][n] = __builtin_amdgcn_mfma_f32_16x16x32_bf16(ahf[m], blf[n], acc[m][n], 0, 0, 0);
    }

    // C/D layout: col = lane&15, row = (lane>>4)*4 + j
#pragma unroll
    for (int m = 0; m < 4; ++m) {
        int row0 = bm + wr + m * 16 + kq * 4;
#pragma unroll
        for (int j = 0; j < 4; ++j) {
            float* Cr = C + (size_t)(row0 + j) * ldc + bn + wc + fr;
#pragma unroll
            for (int n = 0; n < 4; ++n) Cr[n * 16] = acc[m][n][j];
        }
    }
}

// ---------------- causal depthwise conv (D_CONV=4) + SiLU ----------------
__global__ __launch_bounds__(256) void conv_silu_k(
    const float* __restrict__ xz, const float* __restrict__ conv_w,
    const float* __restrict__ conv_b, float* __restrict__ x_conv)
{
    int idx = blockIdx.x * 256 + threadIdx.x;   // ROWS * 512 total
    int q = idx & 511;
    int r = idx >> 9;
    int b = r >> 11, t = r & (SEQL - 1);
    int d0 = q << 2;
    float w[4][4];
#pragma unroll
    for (int c = 0; c < 4; ++c) *(float4*)w[c] = *(const float4*)&conv_w[(d0 + c) * 4];
    float4 acc = *(const float4*)&conv_b[d0];
    const float* xp = xz + (size_t)(b * SEQL) * XZ_LD + d0;
#pragma unroll
    for (int k = 0; k < 4; ++k) {
        int t2 = t - 3 + k;
        if (t2 >= 0) {
            float4 v = *(const float4*)(xp + (size_t)t2 * XZ_LD);
            acc.x = fmaf(v.x, w[0][k], acc.x);
            acc.y = fmaf(v.y, w[1][k], acc.y);
            acc.z = fmaf(v.z, w[2][k], acc.z);
            acc.w = fmaf(v.w, w[3][k], acc.w);
        }
    }
    acc.x *= sigmoidf_(acc.x);
    acc.y *= sigmoidf_(acc.y);
    acc.z *= sigmoidf_(acc.z);
    acc.w *= sigmoidf_(acc.w);
    *(float4*)&x_conv[(size_t)r * D_INNER + d0] = acc;
}

// ---------------- x_proj: 33 dots of length 2048 per row -> A_bar/B_bar/C ----------------
__global__ __launch_bounds__(256) void proj_k(
    const float* __restrict__ x_conv, const float* __restrict__ W_xproj,
    const float* __restrict__ A_log,
    float* __restrict__ Abar, float* __restrict__ Bbar, float* __restrict__ Cmat)
{
    __shared__ float sdbl[4][33];
    int tid = threadIdx.x;
    int w = tid >> 6, lane = tid & 63;
    int row = blockIdx.x * 4 + w;
    const float* xrow = x_conv + (size_t)row * D_INNER;
    float4 xr[8];
#pragma unroll
    for (int it = 0; it < 8; ++it)
        xr[it] = *(const float4*)&xrow[it * 256 + lane * 4];

    for (int j = 0; j < 33; ++j) {
        const float* wrow = W_xproj + j * D_INNER;
        float accv = 0.f;
#pragma unroll
        for (int it = 0; it < 8; ++it) {
            float4 wv = *(const float4*)&wrow[it * 256 + lane * 4];
            accv = fmaf(xr[it].x, wv.x, accv);
            accv = fmaf(xr[it].y, wv.y, accv);
            accv = fmaf(xr[it].z, wv.z, accv);
            accv = fmaf(xr[it].w, wv.w, accv);
        }
#pragma unroll
        for (int off = 32; off; off >>= 1) accv += __shfl_xor(accv, off);
        if (lane == 0) sdbl[w][j] = accv;
    }
    __syncthreads();
    if (tid < 64) {
        int w2 = tid >> 4, s = tid & 15;
        int row2 = blockIdx.x * 4 + w2;
        float draw = sdbl[w2][32];
        float sp = (draw > 20.f) ? draw : log1pf(__expf(draw));
        float dt = fminf(fmaxf(sp, 0.001f), 0.1f);
        float Aa = -__expf(A_log[s]);
        float dtA = fminf(fmaxf(dt * Aa, -20.f), 0.f);
        Abar[row2 * 16 + s] = __expf(dtA);
        float bb = dt * sdbl[w2][s];
        Bbar[row2 * 16 + s] = fminf(fmaxf(bb, -10.f), 10.f);
        Cmat[row2 * 16 + s] = sdbl[w2][16 + s];
    }
}

// ---------------- SSM scan: 4 lanes per channel (4 states each) ----------------
// grid (D_INNER/SCH, NB), 128 threads. Writes y (fp32) IN PLACE over x_conv
// (each block owns its channel columns; tile-tc writes happen only after tile-tc
// reads are staged, and prefetch reads tile tc+1's rows — disjoint).
#define SCH 32
#define TT 16
__global__ __launch_bounds__(128) void scan_k(
    float* __restrict__ x_conv, const float* __restrict__ xz,
    const float* __restrict__ Abar, const float* __restrict__ Bbar,
    const float* __restrict__ Cmat, const float* __restrict__ D_param)
{
    __shared__ float sX[2][TT][SCH];
    __shared__ float sZ[2][TT][SCH];
    __shared__ __align__(16) float sP[2][TT][48];
    const int tid = threadIdx.x;
    const int b = blockIdx.y, dbase = blockIdx.x * SCH;
    const int ch = tid >> 2, sg = tid & 3;
    const int d = dbase + ch;
    float* xc = x_conv + (size_t)(b * SEQL) * D_INNER + dbase;
    const float* zp = xz + (size_t)(b * SEQL) * XZ_LD + D_INNER + dbase;
    const int pbase0 = (b * SEQL) * 16;

    auto stage = [&](int buf, int tc) {
        int t0 = tc * TT;
#pragma unroll
        for (int i = 0; i < 4; ++i) {
            int idx = i * 128 + tid;     // 0..511
            int t = idx >> 5, c = idx & 31;
            sX[buf][t][c] = xc[(size_t)(t0 + t) * D_INNER + c];
            sZ[buf][t][c] = zp[(size_t)(t0 + t) * XZ_LD + c];
        }
#pragma unroll
        for (int i = 0; i < 2; ++i) {
            int idx = i * 128 + tid;     // 0..255
            int t = idx >> 4, s = idx & 15;
            int g = pbase0 + t0 * 16 + idx;
            sP[buf][t][s]      = Abar[g];
            sP[buf][t][16 + s] = Bbar[g];
            sP[buf][t][32 + s] = Cmat[g];
        }
    };

    stage(0, 0);
    float h0 = 0.f, h1 = 0.f, h2 = 0.f, h3 = 0.f;
    float Dp = D_param[d];

    for (int tc = 0; tc < SEQL / TT; ++tc) {
        int buf = tc & 1;
        __syncthreads();
        if (tc + 1 < SEQL / TT) stage(buf ^ 1, tc + 1);
#pragma unroll
        for (int i = 0; i < TT; ++i) {
            float x = sX[buf][i][ch];
            float z = sZ[buf][i][ch];
            const float4* Pf = (const float4*)&sP[buf][i][0];
            float4 Av = Pf[sg], Bv = Pf[4 + sg], Cv = Pf[8 + sg];
            h0 = fminf(fmaxf(fmaf(Bv.x, x, Av.x * h0), -100.f), 100.f);
            h1 = fminf(fmaxf(fmaf(Bv.y, x, Av.y * h1), -100.f), 100.f);
            h2 = fminf(fmaxf(fmaf(Bv.z, x, Av.z * h2), -100.f), 100.f);
            h3 = fminf(fmaxf(fmaf(Bv.w, x, Av.w * h3), -100.f), 100.f);
            float yp = h0 * Cv.x + h1 * Cv.y + h2 * Cv.z + h3 * Cv.w;
            yp += __shfl_xor(yp, 1);
            yp += __shfl_xor(yp, 2);
            if (sg == 0) {
                float o = fmaf(x, Dp, yp * (z * sigmoidf_(z)));
                xc[(size_t)(tc * TT + i) * D_INNER + ch] = o;
            }
        }
    }
}

extern "C" void kernel_launch(void* const* d_in, const int* in_sizes, int n_in,
                              void* d_out, int out_size, void* d_ws, size_t ws_size,
                              hipStream_t stream) {
    const float* x       = (const float*)d_in[0];
    const float* W_in    = (const float*)d_in[1];
    const float* conv_w  = (const float*)d_in[2];
    const float* conv_b  = (const float*)d_in[3];
    const float* W_xproj = (const float*)d_in[4];
    const float* A_log   = (const float*)d_in[5];
    const float* D_param = (const float*)d_in[6];
    const float* W_out   = (const float*)d_in[7];
    float* out = (float*)d_out;

    // ---- workspace: exactly the round-1 footprint (202.9 MB), phase-aliased ----
    char* p = (char*)d_ws;
    char* xzB = p;
    float* xz = (float*)xzB;                 // 134.2 MB, live until scan
    p += (size_t)ROWS * XZ_LD * 4;
    char* xcB = p;
    float* x_conv = (float*)xcB;             // 67.1 MB, multi-phase
    p += (size_t)ROWS * D_INNER * 4;
    float* Abar = (float*)p; p += (size_t)ROWS * 16 * 4;
    float* Bbar = (float*)p; p += (size_t)ROWS * 16 * 4;
    float* Cm   = (float*)p; p += (size_t)ROWS * 16 * 4;

    // phase-0 aliases inside xcbuf (GEMM1 inputs; dead once conv writes x_conv)
    unsigned short* xh  = (unsigned short*)xcB;
    unsigned short* xl  = xh + (size_t)ROWS * D_MODEL;
    unsigned short* wih = xl + (size_t)ROWS * D_MODEL;
    unsigned short* wil = wih + (size_t)2 * D_INNER * D_MODEL;   // ends at 48 MiB < 64 MiB

    // phase-3 aliases inside xz region (valid after scan consumed z)
    unsigned short* yh  = (unsigned short*)xzB;
    unsigned short* yl  = yh + (size_t)ROWS * D_INNER;
    unsigned short* woh = yl + (size_t)ROWS * D_INNER;
    unsigned short* wol = woh + (size_t)D_MODEL * D_INNER;       // ends at 75.5 MB < 134 MB

    // 0) split x and W_in to hi/lo bf16
    cvt_k<<<ROWS * D_MODEL / 4 / 256, 256, 0, stream>>>(
        (const float4*)x, (ushort4*)xh, (ushort4*)xl, ROWS * D_MODEL / 4);
    cvt_k<<<2 * D_INNER * D_MODEL / 4 / 256, 256, 0, stream>>>(
        (const float4*)W_in, (ushort4*)wih, (ushort4*)wil, 2 * D_INNER * D_MODEL / 4);
    // 1) xz = x @ W_in^T  (M=8192, N=4096, K=1024)
    gemm_hilo<<<dim3(4096 / 128, ROWS / 128), 256, 0, stream>>>(
        xh, xl, D_MODEL, wih, wil, D_MODEL, xz, XZ_LD, D_MODEL);
    // 2) conv + silu (reads xz, overwrites phase-0 aliases with x_conv)
    conv_silu_k<<<ROWS * 512 / 256, 256, 0, stream>>>(xz, conv_w, conv_b, x_conv);
    // 3) x_proj
    proj_k<<<ROWS / 4, 256, 0, stream>>>(x_conv, W_xproj, A_log, Abar, Bbar, Cm);
    // 4) scan -> y fp32, in place over x_conv
    scan_k<<<dim3(D_INNER / SCH, NB), 128, 0, stream>>>(x_conv, xz, Abar, Bbar, Cm, D_param);
    // 5) split y and W_out to hi/lo (into now-dead xz region)
    cvt_k<<<ROWS * D_INNER / 4 / 256, 256, 0, stream>>>(
        (const float4*)x_conv, (ushort4*)yh, (ushort4*)yl, ROWS * D_INNER / 4);
    cvt_k<<<D_MODEL * D_INNER / 4 / 256, 256, 0, stream>>>(
        (const float4*)W_out, (ushort4*)woh, (ushort4*)wol, D_MODEL * D_INNER / 4);
    // 6) out = y @ W_out^T  (M=8192, N=1024, K=2048)
    gemm_hilo<<<dim3(1024 / 128, ROWS / 128), 256, 0, stream>>>(
        yh, yl, D_INNER, woh, wol, D_INNER, out, D_MODEL, D_INNER);
}

// Round 4
// 784.774 us; speedup vs baseline: 2.5958x; 1.3206x over previous
//
#include <hip/hip_runtime.h>
#include <cmath>

#define D_MODEL 1024
#define D_STATE 16
#define D_INNER 2048
#define NB 4
#define SEQL 2048
#define ROWS (NB*SEQL)        // 8192
#define XZ_LD (2*D_INNER)     // 4096

typedef __attribute__((ext_vector_type(8))) short short8;
typedef __attribute__((ext_vector_type(4))) float f32x4;

__device__ __forceinline__ float sigmoidf_(float v) { return 1.0f / (1.0f + __expf(-v)); }

__device__ __forceinline__ unsigned short bf16rne(float f) {
    unsigned u = __float_as_uint(f);
    unsigned r = (u + 0x7FFFu + ((u >> 16) & 1u)) >> 16;
    return (unsigned short)r;
}

// ---------------- fp32 -> (hi, lo) bf16 split ----------------
__global__ __launch_bounds__(256) void cvt_k(const float4* __restrict__ in,
    ushort4* __restrict__ hi, ushort4* __restrict__ lo, int n4)
{
    int i = blockIdx.x * 256 + threadIdx.x;
    if (i >= n4) return;
    float4 v = in[i];
    ushort4 h, l;
    h.x = bf16rne(v.x); l.x = bf16rne(v.x - __uint_as_float((unsigned)h.x << 16));
    h.y = bf16rne(v.y); l.y = bf16rne(v.y - __uint_as_float((unsigned)h.y << 16));
    h.z = bf16rne(v.z); l.z = bf16rne(v.z - __uint_as_float((unsigned)h.z << 16));
    h.w = bf16rne(v.w); l.w = bf16rne(v.w - __uint_as_float((unsigned)h.w << 16));
    hi[i] = h; lo[i] = l;
}

// ---------------- bf16x3 split-precision MFMA GEMM (NT): C = A*B^T ----------------
#define GLDS(gp, lp) __builtin_amdgcn_global_load_lds( \
    (const __attribute__((address_space(1))) void*)(gp), \
    (__attribute__((address_space(3))) void*)(lp), 16, 0, 0)

__global__ __launch_bounds__(256) void gemm_hilo(
    const unsigned short* __restrict__ Ah, const unsigned short* __restrict__ Al, int lda,
    const unsigned short* __restrict__ Bh, const unsigned short* __restrict__ Bl, int ldb,
    float* __restrict__ C, int ldc, int K)
{
    __shared__ __align__(16) unsigned short sA[8 * 128 * 8];   // 16 KiB
    __shared__ __align__(16) unsigned short sB[8 * 128 * 8];   // 16 KiB
    const int tid = threadIdx.x;
    const int bm = blockIdx.y * 128, bn = blockIdx.x * 128;
    const int wave = tid >> 6, lane = tid & 63;
    const int wr = (wave >> 1) * 64, wc = (wave & 1) * 64;
    const int fr = lane & 15, kq = lane >> 4;

    const unsigned short* agp[4];
    const unsigned short* bgp[4];
#pragma unroll
    for (int run = 0; run < 4; ++run) {
        int c = run * 256 + tid, s = c >> 7, r = c & 127;
        const unsigned short* ab = (s < 4) ? Ah : Al;
        const unsigned short* bb = (s < 4) ? Bh : Bl;
        agp[run] = ab + (size_t)(bm + r) * lda + (s & 3) * 8;
        bgp[run] = bb + (size_t)(bn + r) * ldb + (s & 3) * 8;
    }

    f32x4 zero = {0.f, 0.f, 0.f, 0.f};
    f32x4 acc[4][4];
#pragma unroll
    for (int m = 0; m < 4; ++m)
#pragma unroll
        for (int n = 0; n < 4; ++n) acc[m][n] = zero;

    for (int k0 = 0; k0 < K; k0 += 32) {
        __syncthreads();
#pragma unroll
        for (int run = 0; run < 4; ++run) {
            unsigned lds_off = (unsigned)(run * 256 + (tid & 192)) * 8;
            GLDS(agp[run], sA + lds_off);
            GLDS(bgp[run], sB + lds_off);
            agp[run] += 32; bgp[run] += 32;
        }
        __syncthreads();

        short8 ahf[4], alf[4], bhf[4], blf[4];
#pragma unroll
        for (int m = 0; m < 4; ++m) {
            int ra = wr + m * 16 + fr;
            ahf[m] = *(const short8*)&sA[(kq * 128 + ra) * 8];
            alf[m] = *(const short8*)&sA[((kq + 4) * 128 + ra) * 8];
        }
#pragma unroll
        for (int n = 0; n < 4; ++n) {
            int rb = wc + n * 16 + fr;
            bhf[n] = *(const short8*)&sB[(kq * 128 + rb) * 8];
            blf[n] = *(const short8*)&sB[((kq + 4) * 128 + rb) * 8];
        }
#pragma unroll
        for (int m = 0; m < 4; ++m)
#pragma unroll
            for (int n = 0; n < 4; ++n)
                acc[m][n] = __builtin_amdgcn_mfma_f32_16x16x32_bf16(ahf[m], bhf[n], acc[m][n], 0, 0, 0);
#pragma unroll
        for (int m = 0; m < 4; ++m)
#pragma unroll
            for (int n = 0; n < 4; ++n)
                acc[m][n] = __builtin_amdgcn_mfma_f32_16x16x32_bf16(alf[m], bhf[n], acc[m][n], 0, 0, 0);
#pragma unroll
        for (int m = 0; m < 4; ++m)
#pragma unroll
            for (int n = 0; n < 4; ++n)
                acc[m][n] = __builtin_amdgcn_mfma_f32_16x16x32_bf16(ahf[m], blf[n], acc[m][n], 0, 0, 0);
    }

    // C/D layout: col = lane&15, row = (lane>>4)*4 + j
#pragma unroll
    for (int m = 0; m < 4; ++m) {
        int row0 = bm + wr + m * 16 + kq * 4;
#pragma unroll
        for (int j = 0; j < 4; ++j) {
            float* Cr = C + (size_t)(row0 + j) * ldc + bn + wc + fr;
#pragma unroll
            for (int n = 0; n < 4; ++n) Cr[n * 16] = acc[m][n][j];
        }
    }
}

// ---------------- causal depthwise conv (D_CONV=4) + SiLU ----------------
__global__ __launch_bounds__(256) void conv_silu_k(
    const float* __restrict__ xz, const float* __restrict__ conv_w,
    const float* __restrict__ conv_b, float* __restrict__ x_conv)
{
    int idx = blockIdx.x * 256 + threadIdx.x;   // ROWS * 512 total
    int q = idx & 511;
    int r = idx >> 9;
    int b = r >> 11, t = r & (SEQL - 1);
    int d0 = q << 2;
    float w[4][4];
#pragma unroll
    for (int c = 0; c < 4; ++c) *(float4*)w[c] = *(const float4*)&conv_w[(d0 + c) * 4];
    float4 acc = *(const float4*)&conv_b[d0];
    const float* xp = xz + (size_t)(b * SEQL) * XZ_LD + d0;
#pragma unroll
    for (int k = 0; k < 4; ++k) {
        int t2 = t - 3 + k;
        if (t2 >= 0) {
            float4 v = *(const float4*)(xp + (size_t)t2 * XZ_LD);
            acc.x = fmaf(v.x, w[0][k], acc.x);
            acc.y = fmaf(v.y, w[1][k], acc.y);
            acc.z = fmaf(v.z, w[2][k], acc.z);
            acc.w = fmaf(v.w, w[3][k], acc.w);
        }
    }
    acc.x *= sigmoidf_(acc.x);
    acc.y *= sigmoidf_(acc.y);
    acc.z *= sigmoidf_(acc.z);
    acc.w *= sigmoidf_(acc.w);
    *(float4*)&x_conv[(size_t)r * D_INNER + d0] = acc;
}

// ---------------- x_proj: 33 dots of length 2048 per row -> A_bar/B_bar/C ----------------
__global__ __launch_bounds__(256) void proj_k(
    const float* __restrict__ x_conv, const float* __restrict__ W_xproj,
    const float* __restrict__ A_log,
    float* __restrict__ Abar, float* __restrict__ Bbar, float* __restrict__ Cmat)
{
    __shared__ float sdbl[4][33];
    int tid = threadIdx.x;
    int w = tid >> 6, lane = tid & 63;
    int row = blockIdx.x * 4 + w;
    const float* xrow = x_conv + (size_t)row * D_INNER;
    float4 xr[8];
#pragma unroll
    for (int it = 0; it < 8; ++it)
        xr[it] = *(const float4*)&xrow[it * 256 + lane * 4];

    for (int j = 0; j < 33; ++j) {
        const float* wrow = W_xproj + j * D_INNER;
        float accv = 0.f;
#pragma unroll
        for (int it = 0; it < 8; ++it) {
            float4 wv = *(const float4*)&wrow[it * 256 + lane * 4];
            accv = fmaf(xr[it].x, wv.x, accv);
            accv = fmaf(xr[it].y, wv.y, accv);
            accv = fmaf(xr[it].z, wv.z, accv);
            accv = fmaf(xr[it].w, wv.w, accv);
        }
#pragma unroll
        for (int off = 32; off; off >>= 1) accv += __shfl_xor(accv, off);
        if (lane == 0) sdbl[w][j] = accv;
    }
    __syncthreads();
    if (tid < 64) {
        int w2 = tid >> 4, s = tid & 15;
        int row2 = blockIdx.x * 4 + w2;
        float draw = sdbl[w2][32];
        float sp = (draw > 20.f) ? draw : log1pf(__expf(draw));
        float dt = fminf(fmaxf(sp, 0.001f), 0.1f);
        float Aa = -__expf(A_log[s]);
        float dtA = fminf(fmaxf(dt * Aa, -20.f), 0.f);
        Abar[row2 * 16 + s] = __expf(dtA);
        float bb = dt * sdbl[w2][s];
        Bbar[row2 * 16 + s] = fminf(fmaxf(bb, -10.f), 10.f);
        Cmat[row2 * 16 + s] = sdbl[w2][16 + s];
    }
}

// ---------------- SSM scan v3: 1 state per lane, 16 lanes per channel ----------------
// grid (D_INNER/16, NB), 256 threads (16 channels/block, 8 waves/CU).
// Phase A (per 16-step chunk): h-recurrence + partial p[t]=h*C in registers (no cross-lane).
// Phase B: wave-private LDS transpose; lane (ch, t=s) sums 16 states, applies gating,
// writes y fp32 in place over x_conv.
#define SCH 16
#define TT 16
__global__ __launch_bounds__(256) void scan_k(
    float* __restrict__ x_conv, const float* __restrict__ xz,
    const float* __restrict__ Abar, const float* __restrict__ Bbar,
    const float* __restrict__ Cmat, const float* __restrict__ D_param)
{
    __shared__ __align__(16) float sXa[2][SCH][TT];        // [ch][t]
    __shared__ float sZp[2][SCH][TT + 1];                  // [ch][t], pad 17
    __shared__ __align__(16) float sPa[2][16][20];         // [s][t], pad 20
    __shared__ __align__(16) float sPb[2][16][20];
    __shared__ __align__(16) float sPc[2][16][20];
    __shared__ __align__(16) float sT[SCH][328];           // [ch][t*20 + s], +8/ch bank skew

    const int tid = threadIdx.x;
    const int b = blockIdx.y, dbase = blockIdx.x * SCH;
    const int chl = tid >> 4, s = tid & 15;
    float* xc = x_conv + (size_t)(b * SEQL) * D_INNER + dbase;
    const float* zp = xz + (size_t)(b * SEQL) * XZ_LD + D_INNER + dbase;
    const int pbase0 = (b * SEQL) * 16;

    // staging thread mapping: st = tid>>4 (t), sc = tid&15 (channel) -> coalesced global
    const int st = tid >> 4, sc = tid & 15;

    auto stage = [&](int buf, int tc) {
        int t0 = tc * TT;
        sXa[buf][sc][st] = xc[(size_t)(t0 + st) * D_INNER + sc];
        sZp[buf][sc][st] = zp[(size_t)(t0 + st) * XZ_LD + sc];
        int g = pbase0 + t0 * 16 + tid;           // tid = st*16 + sc; here sc is state idx
        sPa[buf][sc][st] = Abar[g];
        sPb[buf][sc][st] = Bbar[g];
        sPc[buf][sc][st] = Cmat[g];
    };

    stage(0, 0);
    float h = 0.f;
    const float Dp = D_param[dbase + chl];

    for (int tc = 0; tc < SEQL / TT; ++tc) {
        int buf = tc & 1;
        __syncthreads();                          // staging of `buf` complete
        if (tc + 1 < SEQL / TT) stage(buf ^ 1, tc + 1);

        // ---- phase A: 16 steps, h-chain + partials in regs ----
        float p[16];
#pragma unroll
        for (int q = 0; q < 4; ++q) {
            float4 a4 = *(const float4*)&sPa[buf][s][q * 4];
            float4 b4 = *(const float4*)&sPb[buf][s][q * 4];
            float4 c4 = *(const float4*)&sPc[buf][s][q * 4];
            float4 x4 = *(const float4*)&sXa[buf][chl][q * 4];   // broadcast
            h = fminf(fmaxf(fmaf(b4.x, x4.x, a4.x * h), -100.f), 100.f); p[q * 4 + 0] = h * c4.x;
            h = fminf(fmaxf(fmaf(b4.y, x4.y, a4.y * h), -100.f), 100.f); p[q * 4 + 1] = h * c4.y;
            h = fminf(fmaxf(fmaf(b4.z, x4.z, a4.z * h), -100.f), 100.f); p[q * 4 + 2] = h * c4.z;
            h = fminf(fmaxf(fmaf(b4.w, x4.w, a4.w * h), -100.f), 100.f); p[q * 4 + 3] = h * c4.w;
        }

        // ---- phase B: wave-private transpose + reduce + gating ----
#pragma unroll
        for (int i = 0; i < 16; ++i) sT[chl][i * 20 + s] = p[i];
        // lane handles t = s
        float4 r0 = *(const float4*)&sT[chl][s * 20 + 0];
        float4 r1 = *(const float4*)&sT[chl][s * 20 + 4];
        float4 r2 = *(const float4*)&sT[chl][s * 20 + 8];
        float4 r3 = *(const float4*)&sT[chl][s * 20 + 12];
        float4 rs = make_float4(r0.x + r1.x + r2.x + r3.x, r0.y + r1.y + r2.y + r3.y,
                                r0.z + r1.z + r2.z + r3.z, r0.w + r1.w + r2.w + r3.w);
        float ysum = (rs.x + rs.y) + (rs.z + rs.w);
        float z = sZp[buf][chl][s];
        float x = sXa[buf][chl][s];
        float o = fmaf(x, Dp, ysum * (z * sigmoidf_(z)));
        xc[(size_t)(tc * TT + s) * D_INNER + chl] = o;
    }
}

extern "C" void kernel_launch(void* const* d_in, const int* in_sizes, int n_in,
                              void* d_out, int out_size, void* d_ws, size_t ws_size,
                              hipStream_t stream) {
    const float* x       = (const float*)d_in[0];
    const float* W_in    = (const float*)d_in[1];
    const float* conv_w  = (const float*)d_in[2];
    const float* conv_b  = (const float*)d_in[3];
    const float* W_xproj = (const float*)d_in[4];
    const float* A_log   = (const float*)d_in[5];
    const float* D_param = (const float*)d_in[6];
    const float* W_out   = (const float*)d_in[7];
    float* out = (float*)d_out;

    // ---- workspace: round-1 footprint (202.9 MB), phase-aliased ----
    char* p = (char*)d_ws;
    char* xzB = p;
    float* xz = (float*)xzB;                 // 134.2 MB
    p += (size_t)ROWS * XZ_LD * 4;
    char* xcB = p;
    float* x_conv = (float*)xcB;             // 67.1 MB
    p += (size_t)ROWS * D_INNER * 4;
    float* Abar = (float*)p; p += (size_t)ROWS * 16 * 4;
    float* Bbar = (float*)p; p += (size_t)ROWS * 16 * 4;
    float* Cm   = (float*)p; p += (size_t)ROWS * 16 * 4;

    // phase-0 aliases inside xcbuf (GEMM1 inputs; dead once conv writes x_conv)
    unsigned short* xh  = (unsigned short*)xcB;
    unsigned short* xl  = xh + (size_t)ROWS * D_MODEL;
    unsigned short* wih = xl + (size_t)ROWS * D_MODEL;
    unsigned short* wil = wih + (size_t)2 * D_INNER * D_MODEL;

    // phase-3 aliases inside xz region (valid after scan consumed z)
    unsigned short* yh  = (unsigned short*)xzB;
    unsigned short* yl  = yh + (size_t)ROWS * D_INNER;
    unsigned short* woh = yl + (size_t)ROWS * D_INNER;
    unsigned short* wol = woh + (size_t)D_MODEL * D_INNER;

    cvt_k<<<ROWS * D_MODEL / 4 / 256, 256, 0, stream>>>(
        (const float4*)x, (ushort4*)xh, (ushort4*)xl, ROWS * D_MODEL / 4);
    cvt_k<<<2 * D_INNER * D_MODEL / 4 / 256, 256, 0, stream>>>(
        (const float4*)W_in, (ushort4*)wih, (ushort4*)wil, 2 * D_INNER * D_MODEL / 4);
    gemm_hilo<<<dim3(4096 / 128, ROWS / 128), 256, 0, stream>>>(
        xh, xl, D_MODEL, wih, wil, D_MODEL, xz, XZ_LD, D_MODEL);
    conv_silu_k<<<ROWS * 512 / 256, 256, 0, stream>>>(xz, conv_w, conv_b, x_conv);
    proj_k<<<ROWS / 4, 256, 0, stream>>>(x_conv, W_xproj, A_log, Abar, Bbar, Cm);
    scan_k<<<dim3(D_INNER / SCH, NB), 256, 0, stream>>>(x_conv, xz, Abar, Bbar, Cm, D_param);
    cvt_k<<<ROWS * D_INNER / 4 / 256, 256, 0, stream>>>(
        (const float4*)x_conv, (ushort4*)yh, (ushort4*)yl, ROWS * D_INNER / 4);
    cvt_k<<<D_MODEL * D_INNER / 4 / 256, 256, 0, stream>>>(
        (const float4*)W_out, (ushort4*)woh, (ushort4*)wol, D_MODEL * D_INNER / 4);
    gemm_hilo<<<dim3(1024 / 128, ROWS / 128), 256, 0, stream>>>(
        yh, yl, D_INNER, woh, wol, D_INNER, out, D_MODEL, D_INNER);
}